// Round 5
// baseline (309.518 us; speedup 1.0000x reference)
//
#include <hip/hip_runtime.h>

#define N_NODES 50000
#define N_EDGES 600000
#define N_GRAPHS 128
#define DIM 128
#define NLAYERS 3
#define NOUT 10
#define LSTRIDE 136  // LDS tile row stride in elems (272 B: 16B-aligned, conflict-benign)

typedef unsigned short u16;
typedef __attribute__((ext_vector_type(8))) short bf16x8;
typedef __attribute__((ext_vector_type(4))) float f32x4;

__device__ __forceinline__ float bf2f(u16 v) {
    unsigned u = ((unsigned)v) << 16;
    return __builtin_bit_cast(float, u);
}
__device__ __forceinline__ u16 f2bf(float f) {  // round-to-nearest-even
    unsigned u = __builtin_bit_cast(unsigned, f);
    u = u + 0x7fffu + ((u >> 16) & 1u);
    return (u16)(u >> 16);
}

// ---------------------------------------------------------------------------
// init: deg=0, x->bf16, W pre-swizzle into MFMA B-fragment order
__global__ void init_all(int* __restrict__ deg, u16* __restrict__ xb,
                         const float* __restrict__ x, u16* __restrict__ Wswz,
                         const float* __restrict__ convW1, const float* __restrict__ convW2) {
    int i = blockIdx.x * blockDim.x + threadIdx.x;
    if (i < N_NODES) deg[i] = 0;
    if (i < 6 * 16384) {
        int j = i & 7, lane = (i >> 3) & 63, cb = (i >> 9) & 7, kc = (i >> 12) & 3, w = i >> 14;
        int k = kc * 32 + ((lane >> 4) << 3) + j;
        int c = (cb << 4) + (lane & 15);
        const float* W = (w < 3) ? (convW1 + (size_t)w * 16384) : (convW2 + (size_t)(w - 3) * 16384);
        Wswz[i] = f2bf(W[k * DIM + c]);
    }
    if (i < N_NODES * DIM / 4) {
        float4 v = ((const float4*)x)[i];
        ushort4 o;
        o.x = f2bf(v.x); o.y = f2bf(v.y); o.z = f2bf(v.z); o.w = f2bf(v.w);
        ((ushort4*)xb)[i] = o;
    }
}

__global__ void hist_deg(int* __restrict__ deg, const int* __restrict__ dsts, int nE) {
    int e = blockIdx.x * blockDim.x + threadIdx.x;
    if (e < nE) atomicAdd(&deg[dsts[e]], 1);
}

__global__ void scan_chunks(int* __restrict__ partial, int* __restrict__ sums,
                            const int* __restrict__ deg, int n) {
    int i = blockIdx.x * blockDim.x + threadIdx.x;
    int lane = threadIdx.x & 63;
    int v = (i < n) ? deg[i] : 0;
#pragma unroll
    for (int off = 1; off < 64; off <<= 1) {
        int t = __shfl_up(v, off);
        if (lane >= off) v += t;
    }
    if (i < n) partial[i] = v;
    if (lane == 63) sums[i >> 6] = v;
}

__global__ void scan_sums(int* __restrict__ offs, const int* __restrict__ sums, int nc) {
    int lane = threadIdx.x;  // 64 threads
    int carry = 0;
    for (int base = 0; base < nc; base += 64) {
        int idx = base + lane;
        int v = (idx < nc) ? sums[idx] : 0;
        int inc = v;
#pragma unroll
        for (int off = 1; off < 64; off <<= 1) {
            int t = __shfl_up(inc, off);
            if (lane >= off) inc += t;
        }
        if (idx < nc) offs[idx] = inc - v + carry;
        carry += __shfl(inc, 63);
    }
}

__global__ void finalize_rowptr(int* __restrict__ rowptr, int* __restrict__ cursor,
                                const int* __restrict__ partial, const int* __restrict__ offs,
                                const int* __restrict__ deg, int n) {
    int i = blockIdx.x * blockDim.x + threadIdx.x;
    if (i == 0) rowptr[0] = 0;
    if (i < n) {
        int incl = partial[i] + offs[i >> 6];
        rowptr[i + 1] = incl;
        cursor[i] = incl - deg[i];
    }
}

__global__ void fill_csr(int* __restrict__ csr, int* __restrict__ cursor,
                         const int* __restrict__ srcs, const int* __restrict__ dsts, int nE) {
    int e = blockIdx.x * blockDim.x + threadIdx.x;
    if (e >= nE) return;
    int d = dsts[e];
    int p = atomicAdd(&cursor[d], 1);
    csr[p] = srcs[e];
}

// ---------------------------------------------------------------------------
// Fused GIN layer: out = relu(MLP2(relu(BN(MLP1(gather(x))))))
// Block = 4 waves x 16 rows. All LDS regions are wave-private -> no barriers.
// LDS tile layout: [16 rows][LSTRIDE elems] bf16 per wave region.
// A-frag read: lane l -> row (l&15), elems kc*32+(l>>4)*8 (ds_read_b128).
// W fragments read from pre-swizzled global (L2-resident).
__global__ __launch_bounds__(256, 4) void layer_fused(
    u16* __restrict__ out, const u16* __restrict__ x,
    const int* __restrict__ rowptr, const int* __restrict__ csr,
    const u16* __restrict__ W1f, const u16* __restrict__ W2f,
    const float* __restrict__ b1, const float* __restrict__ g1,
    const float* __restrict__ bt1, const float* __restrict__ b2) {
    __shared__ u16 lds[4][2][16 * LSTRIDE];  // 34816 B
    const int wv = threadIdx.x >> 6;
    const int lane = threadIdx.x & 63;
    const int row0 = blockIdx.x * 64 + wv * 16;
    u16* A = lds[wv][0];
    u16* H = lds[wv][1];

    // ---- phase 1: gather 16 rows (agg = x[row] + sum of neighbor rows) ----
    for (int i = 0; i < 16; ++i) {
        const int grow = row0 + i;
        float ax = 0.f, ay = 0.f;
        if (grow < N_NODES) {
            const size_t coff = (size_t)lane * 2;
            ushort2 self = *(const ushort2*)(x + (size_t)grow * DIM + coff);
            ax = bf2f(self.x); ay = bf2f(self.y);
            int beg = rowptr[grow], end = rowptr[grow + 1];
            int j = beg;
            for (; j + 4 <= end; j += 4) {
                int s0 = csr[j], s1 = csr[j + 1], s2 = csr[j + 2], s3 = csr[j + 3];
                ushort2 v0 = *(const ushort2*)(x + (size_t)s0 * DIM + coff);
                ushort2 v1 = *(const ushort2*)(x + (size_t)s1 * DIM + coff);
                ushort2 v2 = *(const ushort2*)(x + (size_t)s2 * DIM + coff);
                ushort2 v3 = *(const ushort2*)(x + (size_t)s3 * DIM + coff);
                ax += (bf2f(v0.x) + bf2f(v1.x)) + (bf2f(v2.x) + bf2f(v3.x));
                ay += (bf2f(v0.y) + bf2f(v1.y)) + (bf2f(v2.y) + bf2f(v3.y));
            }
            for (; j < end; ++j) {
                int s = csr[j];
                ushort2 v = *(const ushort2*)(x + (size_t)s * DIM + coff);
                ax += bf2f(v.x);
                ay += bf2f(v.y);
            }
        }
        ushort2 o; o.x = f2bf(ax); o.y = f2bf(ay);
        *(ushort2*)&A[i * LSTRIDE + lane * 2] = o;
    }

    const float inv = rsqrtf(1.f + 1e-5f);
    const int col0 = lane & 15;
    const int rb = (lane >> 4) << 2;  // row base within wave tile for C/D
    const int fragoff = ((lane & 15) * LSTRIDE) + ((lane >> 4) << 3);

    // ---- phase 2: GEMM1 + BN + ReLU -> H ----
    {
        f32x4 acc[8];
#pragma unroll
        for (int cb = 0; cb < 8; ++cb) acc[cb] = (f32x4){0.f, 0.f, 0.f, 0.f};
#pragma unroll
        for (int kc = 0; kc < 4; ++kc) {
            bf16x8 a = *(const bf16x8*)&A[fragoff + kc * 32];
#pragma unroll
            for (int cb = 0; cb < 8; ++cb) {
                bf16x8 bb = *(const bf16x8*)(W1f + ((((kc << 3) + cb) << 6 | lane) << 3));
                acc[cb] = __builtin_amdgcn_mfma_f32_16x16x32_bf16(a, bb, acc[cb], 0, 0, 0);
            }
        }
#pragma unroll
        for (int cb = 0; cb < 8; ++cb) {
            const int c = (cb << 4) + col0;
            const float bias = b1[c];
            const float sg = inv * g1[c];
            const float st = bt1[c];
#pragma unroll
            for (int q = 0; q < 4; ++q) {
                float v = (acc[cb][q] + bias) * sg + st;
                H[(rb + q) * LSTRIDE + c] = f2bf(fmaxf(v, 0.f));
            }
        }
    }

    // ---- phase 3: GEMM2 + bias + ReLU -> A (reused as output staging) ----
    {
        f32x4 acc[8];
#pragma unroll
        for (int cb = 0; cb < 8; ++cb) acc[cb] = (f32x4){0.f, 0.f, 0.f, 0.f};
#pragma unroll
        for (int kc = 0; kc < 4; ++kc) {
            bf16x8 a = *(const bf16x8*)&H[fragoff + kc * 32];
#pragma unroll
            for (int cb = 0; cb < 8; ++cb) {
                bf16x8 bb = *(const bf16x8*)(W2f + ((((kc << 3) + cb) << 6 | lane) << 3));
                acc[cb] = __builtin_amdgcn_mfma_f32_16x16x32_bf16(a, bb, acc[cb], 0, 0, 0);
            }
        }
#pragma unroll
        for (int cb = 0; cb < 8; ++cb) {
            const int c = (cb << 4) + col0;
            const float bias = b2[c];
#pragma unroll
            for (int q = 0; q < 4; ++q) {
                float v = acc[cb][q] + bias;
                A[(rb + q) * LSTRIDE + c] = f2bf(fmaxf(v, 0.f));
            }
        }
    }

    // ---- phase 4: coalesced copy-out (2 rows / pass, 8B / lane) ----
#pragma unroll
    for (int it = 0; it < 8; ++it) {
        const int r = it * 2 + (lane >> 5);
        const int grow = row0 + r;
        const int m = lane & 31;
        uint2 v = *(const uint2*)&A[r * LSTRIDE + m * 4];
        if (grow < N_NODES) *(uint2*)(out + (size_t)grow * DIM + m * 4) = v;
    }
}

// ---------------------------------------------------------------------------
// Fused tail: pool (block-per-graph, batch sorted) + final MLP
__global__ __launch_bounds__(128) void tail_fused(float* __restrict__ out,
                                                  const u16* __restrict__ x,
                                                  const int* __restrict__ batch,
                                                  const float* __restrict__ mW1,
                                                  const float* __restrict__ mb1,
                                                  const float* __restrict__ mg,
                                                  const float* __restrict__ mbt,
                                                  const float* __restrict__ mW2,
                                                  const float* __restrict__ mb2) {
    const int g = blockIdx.x;
    const int c = threadIdx.x;
    __shared__ float pl[DIM];
    __shared__ float hd[DIM];
    __shared__ int sbeg, send;
    if (c == 0) {
        int lo = 0, hi = N_NODES;
        while (lo < hi) { int m = (lo + hi) >> 1; if (batch[m] < g) lo = m + 1; else hi = m; }
        sbeg = lo;
        lo = 0; hi = N_NODES;
        while (lo < hi) { int m = (lo + hi) >> 1; if (batch[m] < g + 1) lo = m + 1; else hi = m; }
        send = lo;
    }
    __syncthreads();
    float acc = 0.f;
    int n = sbeg;
    for (; n + 4 <= send; n += 4) {
        acc += bf2f(x[(size_t)n * DIM + c]) + bf2f(x[(size_t)(n + 1) * DIM + c]) +
               bf2f(x[(size_t)(n + 2) * DIM + c]) + bf2f(x[(size_t)(n + 3) * DIM + c]);
    }
    for (; n < send; ++n) acc += bf2f(x[(size_t)n * DIM + c]);
    pl[c] = acc;
    __syncthreads();

    float s = 0.f;
#pragma unroll 4
    for (int k = 0; k < DIM; ++k) s += pl[k] * mW1[k * DIM + c];
    const float inv = rsqrtf(1.f + 1e-5f);
    s = (s + mb1[c]) * (inv * mg[c]) + mbt[c];
    hd[c] = fmaxf(s, 0.f);
    __syncthreads();

    if (c < NOUT) {
        float o = 0.f;
#pragma unroll 4
        for (int k = 0; k < DIM; ++k) o += hd[k] * mW2[k * NOUT + c];
        out[g * NOUT + c] = o + mb2[c];
    }
}

// ---------------------------------------------------------------------------
extern "C" void kernel_launch(void* const* d_in, const int* in_sizes, int n_in,
                              void* d_out, int out_size, void* d_ws, size_t ws_size,
                              hipStream_t stream) {
    const float* x      = (const float*)d_in[0];
    const int*   ei     = (const int*)d_in[1];
    const int*   batch  = (const int*)d_in[2];
    const float* convW1 = (const float*)d_in[3];
    const float* convb1 = (const float*)d_in[4];
    const float* convg  = (const float*)d_in[5];
    const float* convbt = (const float*)d_in[6];
    const float* convW2 = (const float*)d_in[7];
    const float* convb2 = (const float*)d_in[8];
    const float* mW1    = (const float*)d_in[9];
    const float* mb1    = (const float*)d_in[10];
    const float* mg     = (const float*)d_in[11];
    const float* mbt    = (const float*)d_in[12];
    const float* mW2    = (const float*)d_in[13];
    const float* mb2    = (const float*)d_in[14];
    float* out = (float*)d_out;

    const int* srcs = ei;
    const int* dsts = ei + N_EDGES;

    // workspace layout
    const size_t NF = (size_t)N_NODES * DIM;
    u16* xb0  = (u16*)d_ws;       // bf16 input features
    u16* bufA = xb0 + NF;
    u16* bufB = bufA + NF;
    u16* Wswz = bufB + NF;        // 6*16384 bf16
    int* deg     = (int*)(Wswz + 6 * 16384);
    int* cursor  = deg + N_NODES;
    int* rowptr  = cursor + N_NODES;          // N_NODES+1
    int* partial = rowptr + (N_NODES + 1);
    int* sums    = partial + N_NODES;          // 1024 w/ slack
    int* offs    = sums + 1024;                // 1024
    int* csr     = offs + 1024;                // N_EDGES

    const int NCHUNK = (N_NODES + 63) / 64;

    // ---- init + CSR build ----
    init_all<<<(N_NODES * DIM / 4 + 255) / 256, 256, 0, stream>>>(deg, xb0, x, Wswz, convW1, convW2);
    hist_deg<<<(N_EDGES + 255) / 256, 256, 0, stream>>>(deg, dsts, N_EDGES);
    scan_chunks<<<(N_NODES + 255) / 256, 256, 0, stream>>>(partial, sums, deg, N_NODES);
    scan_sums<<<1, 64, 0, stream>>>(offs, sums, NCHUNK);
    finalize_rowptr<<<(N_NODES + 255) / 256, 256, 0, stream>>>(rowptr, cursor, partial, offs, deg, N_NODES);
    fill_csr<<<(N_EDGES + 255) / 256, 256, 0, stream>>>(csr, cursor, srcs, dsts, N_EDGES);

    // ---- 3 fused GIN layers (ping-pong buffers; gather reads != writes) ----
    const int layerBlocks = (N_NODES + 63) / 64;
    const u16* cur = xb0;
    u16* nxt = bufA;
    for (int l = 0; l < NLAYERS; ++l) {
        layer_fused<<<layerBlocks, 256, 0, stream>>>(
            nxt, cur, rowptr, csr,
            Wswz + (size_t)l * 16384, Wswz + (size_t)(3 + l) * 16384,
            convb1 + l * DIM, convg + l * DIM, convbt + l * DIM, convb2 + l * DIM);
        cur = nxt;
        nxt = (nxt == bufA) ? bufB : bufA;
    }

    // ---- pool + final MLP ----
    tail_fused<<<N_GRAPHS, 128, 0, stream>>>(out, cur, batch, mW1, mb1, mg, mbt, mW2, mb2);
}

// Round 6
// 262.326 us; speedup vs baseline: 1.1799x; 1.1799x over previous
//
#include <hip/hip_runtime.h>

#define N_NODES 50000
#define N_EDGES 600000
#define N_GRAPHS 128
#define DIM 128
#define NLAYERS 3
#define NOUT 10
#define LSTRIDE 136  // LDS row stride in bf16 elems (272B: 16B-aligned, 2-way-conflict max)

typedef unsigned short u16;
typedef __attribute__((ext_vector_type(8))) short bf16x8;
typedef __attribute__((ext_vector_type(4))) float f32x4;

__device__ __forceinline__ float bf2f(u16 v) {
    unsigned u = ((unsigned)v) << 16;
    return __builtin_bit_cast(float, u);
}
__device__ __forceinline__ u16 f2bf(float f) {  // round-to-nearest-even
    unsigned u = __builtin_bit_cast(unsigned, f);
    u = u + 0x7fffu + ((u >> 16) & 1u);
    return (u16)(u >> 16);
}

// ---------------------------------------------------------------------------
// init: deg=0, x->bf16, W pre-swizzle into MFMA B-fragment order
__global__ void init_all(int* __restrict__ deg, u16* __restrict__ xb,
                         const float* __restrict__ x, u16* __restrict__ Wswz,
                         const float* __restrict__ convW1, const float* __restrict__ convW2) {
    int i = blockIdx.x * blockDim.x + threadIdx.x;
    if (i < N_NODES) deg[i] = 0;
    if (i < 6 * 16384) {
        int j = i & 7, lane = (i >> 3) & 63, cb = (i >> 9) & 7, kc = (i >> 12) & 3, w = i >> 14;
        int k = kc * 32 + ((lane >> 4) << 3) + j;
        int c = (cb << 4) + (lane & 15);
        const float* W = (w < 3) ? (convW1 + (size_t)w * 16384) : (convW2 + (size_t)(w - 3) * 16384);
        Wswz[i] = f2bf(W[k * DIM + c]);
    }
    if (i < N_NODES * DIM / 4) {
        float4 v = ((const float4*)x)[i];
        ushort4 o;
        o.x = f2bf(v.x); o.y = f2bf(v.y); o.z = f2bf(v.z); o.w = f2bf(v.w);
        ((ushort4*)xb)[i] = o;
    }
}

__global__ void hist_deg(int* __restrict__ deg, const int* __restrict__ dsts, int nE) {
    int e = blockIdx.x * blockDim.x + threadIdx.x;
    if (e < nE) atomicAdd(&deg[dsts[e]], 1);
}

__global__ void scan_chunks(int* __restrict__ partial, int* __restrict__ sums,
                            const int* __restrict__ deg, int n) {
    int i = blockIdx.x * blockDim.x + threadIdx.x;
    int lane = threadIdx.x & 63;
    int v = (i < n) ? deg[i] : 0;
#pragma unroll
    for (int off = 1; off < 64; off <<= 1) {
        int t = __shfl_up(v, off);
        if (lane >= off) v += t;
    }
    if (i < n) partial[i] = v;
    if (lane == 63) sums[i >> 6] = v;
}

__global__ void scan_sums(int* __restrict__ offs, const int* __restrict__ sums, int nc) {
    int lane = threadIdx.x;  // 64 threads
    int carry = 0;
    for (int base = 0; base < nc; base += 64) {
        int idx = base + lane;
        int v = (idx < nc) ? sums[idx] : 0;
        int inc = v;
#pragma unroll
        for (int off = 1; off < 64; off <<= 1) {
            int t = __shfl_up(inc, off);
            if (lane >= off) inc += t;
        }
        if (idx < nc) offs[idx] = inc - v + carry;
        carry += __shfl(inc, 63);
    }
}

__global__ void finalize_rowptr(int* __restrict__ rowptr, int* __restrict__ cursor,
                                const int* __restrict__ partial, const int* __restrict__ offs,
                                const int* __restrict__ deg, int n) {
    int i = blockIdx.x * blockDim.x + threadIdx.x;
    if (i == 0) rowptr[0] = 0;
    if (i < n) {
        int incl = partial[i] + offs[i >> 6];
        rowptr[i + 1] = incl;
        cursor[i] = incl - deg[i];
    }
}

__global__ void fill_csr(int* __restrict__ csr, int* __restrict__ cursor,
                         const int* __restrict__ srcs, const int* __restrict__ dsts, int nE) {
    int e = blockIdx.x * blockDim.x + threadIdx.x;
    if (e >= nE) return;
    int d = dsts[e];
    int p = atomicAdd(&cursor[d], 1);
    csr[p] = srcs[e];
}

// ---------------------------------------------------------------------------
// gather (bf16): agg[n] = x[n] + sum_{j in csr row n} x[csr[j]]  (one wave/node)
// High TLP (50000 waves) to hide the csr->row dependent-load chain.
__global__ __launch_bounds__(256) void gather_bf(u16* __restrict__ agg,
                                                 const u16* __restrict__ x,
                                                 const int* __restrict__ rowptr,
                                                 const int* __restrict__ csr, int nNodes) {
    int wid = (blockIdx.x * 256 + threadIdx.x) >> 6;
    int lane = threadIdx.x & 63;
    if (wid >= nNodes) return;
    const size_t coff = (size_t)lane * 2;
    ushort2 self = *(const ushort2*)(x + (size_t)wid * DIM + coff);
    float ax = bf2f(self.x), ay = bf2f(self.y);
    int beg = rowptr[wid], end = rowptr[wid + 1];
    int j = beg;
    for (; j + 4 <= end; j += 4) {
        int s0 = csr[j], s1 = csr[j + 1], s2 = csr[j + 2], s3 = csr[j + 3];
        ushort2 v0 = *(const ushort2*)(x + (size_t)s0 * DIM + coff);
        ushort2 v1 = *(const ushort2*)(x + (size_t)s1 * DIM + coff);
        ushort2 v2 = *(const ushort2*)(x + (size_t)s2 * DIM + coff);
        ushort2 v3 = *(const ushort2*)(x + (size_t)s3 * DIM + coff);
        ax += (bf2f(v0.x) + bf2f(v1.x)) + (bf2f(v2.x) + bf2f(v3.x));
        ay += (bf2f(v0.y) + bf2f(v1.y)) + (bf2f(v2.y) + bf2f(v3.y));
    }
    for (; j < end; ++j) {
        int s = csr[j];
        ushort2 v = *(const ushort2*)(x + (size_t)s * DIM + coff);
        ax += bf2f(v.x);
        ay += bf2f(v.y);
    }
    ushort2 o; o.x = f2bf(ax); o.y = f2bf(ay);
    *(ushort2*)(agg + (size_t)wid * DIM + coff) = o;
}

// ---------------------------------------------------------------------------
// Fused 2-layer MLP: out = relu(W2·relu(BN(W1·in + b1)) + b2), bf16 in/out.
// Block = 4 waves x 16 rows = 64 rows. H lives in wave-private LDS (no barriers).
// A frags from global (16B/lane); W frags from pre-swizzled L2-resident global.
// C/D map: col=lane&15, row=(lane>>4)*4+q (verified m89/m91).
__global__ __launch_bounds__(256) void mlp_fused(
    u16* __restrict__ out, const u16* __restrict__ in,
    const u16* __restrict__ W1f, const u16* __restrict__ W2f,
    const float* __restrict__ b1, const float* __restrict__ g1,
    const float* __restrict__ bt1, const float* __restrict__ b2, int nrows) {
    __shared__ u16 lds[4][16 * LSTRIDE];  // 17408 B
    const int wv = threadIdx.x >> 6;
    const int lane = threadIdx.x & 63;
    const int row0 = blockIdx.x * 64 + wv * 16;
    u16* H = lds[wv];

    const float inv = rsqrtf(1.f + 1e-5f);
    const int col0 = lane & 15;
    const int rb = (lane >> 4) << 2;
    const int fragoff = ((lane & 15) * LSTRIDE) + ((lane >> 4) << 3);

    // ---- GEMM1 + BN + ReLU -> H (LDS) ----
    {
        const int arow = min(row0 + (lane & 15), nrows - 1);
        const u16* ap = in + (size_t)arow * DIM + ((lane >> 4) << 3);
        f32x4 acc[8];
#pragma unroll
        for (int cb = 0; cb < 8; ++cb) acc[cb] = (f32x4){0.f, 0.f, 0.f, 0.f};
#pragma unroll
        for (int kc = 0; kc < 4; ++kc) {
            bf16x8 a = *(const bf16x8*)(ap + kc * 32);
#pragma unroll
            for (int cb = 0; cb < 8; ++cb) {
                bf16x8 bb = *(const bf16x8*)(W1f + ((((kc << 3) + cb) << 6 | lane) << 3));
                acc[cb] = __builtin_amdgcn_mfma_f32_16x16x32_bf16(a, bb, acc[cb], 0, 0, 0);
            }
        }
#pragma unroll
        for (int cb = 0; cb < 8; ++cb) {
            const int c = (cb << 4) + col0;
            const float bias = b1[c];
            const float sg = inv * g1[c];
            const float st = bt1[c];
#pragma unroll
            for (int q = 0; q < 4; ++q) {
                float v = (acc[cb][q] + bias) * sg + st;
                H[(rb + q) * LSTRIDE + c] = f2bf(fmaxf(v, 0.f));
            }
        }
    }

    // ---- GEMM2 + bias + ReLU -> H (reused as output staging) ----
    {
        f32x4 acc[8];
#pragma unroll
        for (int cb = 0; cb < 8; ++cb) acc[cb] = (f32x4){0.f, 0.f, 0.f, 0.f};
#pragma unroll
        for (int kc = 0; kc < 4; ++kc) {
            bf16x8 a = *(const bf16x8*)&H[fragoff + kc * 32];
#pragma unroll
            for (int cb = 0; cb < 8; ++cb) {
                bf16x8 bb = *(const bf16x8*)(W2f + ((((kc << 3) + cb) << 6 | lane) << 3));
                acc[cb] = __builtin_amdgcn_mfma_f32_16x16x32_bf16(a, bb, acc[cb], 0, 0, 0);
            }
        }
#pragma unroll
        for (int cb = 0; cb < 8; ++cb) {
            const int c = (cb << 4) + col0;
            const float bias = b2[c];
#pragma unroll
            for (int q = 0; q < 4; ++q) {
                float v = acc[cb][q] + bias;
                H[(rb + q) * LSTRIDE + c] = f2bf(fmaxf(v, 0.f));
            }
        }
    }

    // ---- coalesced copy-out (2 rows / pass, 8B / lane) ----
#pragma unroll
    for (int it = 0; it < 8; ++it) {
        const int r = it * 2 + (lane >> 5);
        const int grow = row0 + r;
        const int m = lane & 31;
        uint2 v = *(const uint2*)&H[r * LSTRIDE + m * 4];
        if (grow < nrows) *(uint2*)(out + (size_t)grow * DIM + m * 4) = v;
    }
}

// ---------------------------------------------------------------------------
// Fused tail: pool (block-per-graph, batch sorted) + final MLP
__global__ __launch_bounds__(128) void tail_fused(float* __restrict__ out,
                                                  const u16* __restrict__ x,
                                                  const int* __restrict__ batch,
                                                  const float* __restrict__ mW1,
                                                  const float* __restrict__ mb1,
                                                  const float* __restrict__ mg,
                                                  const float* __restrict__ mbt,
                                                  const float* __restrict__ mW2,
                                                  const float* __restrict__ mb2) {
    const int g = blockIdx.x;
    const int c = threadIdx.x;
    __shared__ float pl[DIM];
    __shared__ float hd[DIM];
    __shared__ int sbeg, send;
    if (c == 0) {
        int lo = 0, hi = N_NODES;
        while (lo < hi) { int m = (lo + hi) >> 1; if (batch[m] < g) lo = m + 1; else hi = m; }
        sbeg = lo;
        lo = 0; hi = N_NODES;
        while (lo < hi) { int m = (lo + hi) >> 1; if (batch[m] < g + 1) lo = m + 1; else hi = m; }
        send = lo;
    }
    __syncthreads();
    float acc = 0.f;
    int n = sbeg;
    for (; n + 4 <= send; n += 4) {
        acc += bf2f(x[(size_t)n * DIM + c]) + bf2f(x[(size_t)(n + 1) * DIM + c]) +
               bf2f(x[(size_t)(n + 2) * DIM + c]) + bf2f(x[(size_t)(n + 3) * DIM + c]);
    }
    for (; n < send; ++n) acc += bf2f(x[(size_t)n * DIM + c]);
    pl[c] = acc;
    __syncthreads();

    float s = 0.f;
#pragma unroll 4
    for (int k = 0; k < DIM; ++k) s += pl[k] * mW1[k * DIM + c];
    const float inv = rsqrtf(1.f + 1e-5f);
    s = (s + mb1[c]) * (inv * mg[c]) + mbt[c];
    hd[c] = fmaxf(s, 0.f);
    __syncthreads();

    if (c < NOUT) {
        float o = 0.f;
#pragma unroll 4
        for (int k = 0; k < DIM; ++k) o += hd[k] * mW2[k * NOUT + c];
        out[g * NOUT + c] = o + mb2[c];
    }
}

// ---------------------------------------------------------------------------
extern "C" void kernel_launch(void* const* d_in, const int* in_sizes, int n_in,
                              void* d_out, int out_size, void* d_ws, size_t ws_size,
                              hipStream_t stream) {
    const float* x      = (const float*)d_in[0];
    const int*   ei     = (const int*)d_in[1];
    const int*   batch  = (const int*)d_in[2];
    const float* convW1 = (const float*)d_in[3];
    const float* convb1 = (const float*)d_in[4];
    const float* convg  = (const float*)d_in[5];
    const float* convbt = (const float*)d_in[6];
    const float* convW2 = (const float*)d_in[7];
    const float* convb2 = (const float*)d_in[8];
    const float* mW1    = (const float*)d_in[9];
    const float* mb1    = (const float*)d_in[10];
    const float* mg     = (const float*)d_in[11];
    const float* mbt    = (const float*)d_in[12];
    const float* mW2    = (const float*)d_in[13];
    const float* mb2    = (const float*)d_in[14];
    float* out = (float*)d_out;

    const int* srcs = ei;
    const int* dsts = ei + N_EDGES;

    // workspace layout
    const size_t NF = (size_t)N_NODES * DIM;
    u16* xb0    = (u16*)d_ws;     // bf16 input features
    u16* aggbuf = xb0 + NF;
    u16* bufA   = aggbuf + NF;
    u16* bufB   = bufA + NF;
    u16* Wswz   = bufB + NF;      // 6*16384 bf16
    int* deg     = (int*)(Wswz + 6 * 16384);
    int* cursor  = deg + N_NODES;
    int* rowptr  = cursor + N_NODES;          // N_NODES+1
    int* partial = rowptr + (N_NODES + 1);
    int* sums    = partial + N_NODES;          // 1024 w/ slack
    int* offs    = sums + 1024;                // 1024
    int* csr     = offs + 1024;                // N_EDGES

    const int NCHUNK = (N_NODES + 63) / 64;

    // ---- init + CSR build ----
    init_all<<<(N_NODES * DIM / 4 + 255) / 256, 256, 0, stream>>>(deg, xb0, x, Wswz, convW1, convW2);
    hist_deg<<<(N_EDGES + 255) / 256, 256, 0, stream>>>(deg, dsts, N_EDGES);
    scan_chunks<<<(N_NODES + 255) / 256, 256, 0, stream>>>(partial, sums, deg, N_NODES);
    scan_sums<<<1, 64, 0, stream>>>(offs, sums, NCHUNK);
    finalize_rowptr<<<(N_NODES + 255) / 256, 256, 0, stream>>>(rowptr, cursor, partial, offs, deg, N_NODES);
    fill_csr<<<(N_EDGES + 255) / 256, 256, 0, stream>>>(csr, cursor, srcs, dsts, N_EDGES);

    // ---- 3 GIN layers: gather (high-TLP) + fused MLP (compute-dense) ----
    const int gatherBlocks = (N_NODES * 64 + 255) / 256;
    const int mlpBlocks    = (N_NODES + 63) / 64;
    const u16* cur = xb0;
    u16* nxt = bufA;
    for (int l = 0; l < NLAYERS; ++l) {
        gather_bf<<<gatherBlocks, 256, 0, stream>>>(aggbuf, cur, rowptr, csr, N_NODES);
        mlp_fused<<<mlpBlocks, 256, 0, stream>>>(
            nxt, aggbuf,
            Wswz + (size_t)l * 16384, Wswz + (size_t)(3 + l) * 16384,
            convb1 + l * DIM, convg + l * DIM, convbt + l * DIM, convb2 + l * DIM, N_NODES);
        cur = nxt;
        nxt = (nxt == bufA) ? bufB : bufA;
    }

    // ---- pool + final MLP ----
    tail_fused<<<N_GRAPHS, 128, 0, stream>>>(out, cur, batch, mW1, mb1, mg, mbt, mW2, mb2);
}

// Round 7
// 247.357 us; speedup vs baseline: 1.2513x; 1.0605x over previous
//
#include <hip/hip_runtime.h>

#define N_NODES 50000
#define N_EDGES 600000
#define N_GRAPHS 128
#define DIM 128
#define NLAYERS 3
#define NOUT 10
#define LSTRIDE 136  // LDS row stride in bf16 elems (272B: 16B-aligned, 2-way-conflict max)

typedef unsigned short u16;
typedef __attribute__((ext_vector_type(8))) short bf16x8;
typedef __attribute__((ext_vector_type(4))) float f32x4;

__device__ __forceinline__ float bf2f(u16 v) {
    unsigned u = ((unsigned)v) << 16;
    return __builtin_bit_cast(float, u);
}
__device__ __forceinline__ u16 f2bf(float f) {  // round-to-nearest-even
    unsigned u = __builtin_bit_cast(unsigned, f);
    u = u + 0x7fffu + ((u >> 16) & 1u);
    return (u16)(u >> 16);
}

// ---------------------------------------------------------------------------
// init: deg=0, pooled=0, x->bf16, W pre-swizzle into MFMA B-fragment order
__global__ void init_all(int* __restrict__ deg, float* __restrict__ pooled,
                         u16* __restrict__ xb, const float* __restrict__ x,
                         u16* __restrict__ Wswz,
                         const float* __restrict__ convW1, const float* __restrict__ convW2) {
    int i = blockIdx.x * blockDim.x + threadIdx.x;
    if (i < N_NODES) deg[i] = 0;
    if (i < N_GRAPHS * DIM) pooled[i] = 0.f;
    if (i < 6 * 16384) {
        int j = i & 7, lane = (i >> 3) & 63, cb = (i >> 9) & 7, kc = (i >> 12) & 3, w = i >> 14;
        int k = kc * 32 + ((lane >> 4) << 3) + j;
        int c = (cb << 4) + (lane & 15);
        const float* W = (w < 3) ? (convW1 + (size_t)w * 16384) : (convW2 + (size_t)(w - 3) * 16384);
        Wswz[i] = f2bf(W[k * DIM + c]);
    }
    if (i < N_NODES * DIM / 4) {
        float4 v = ((const float4*)x)[i];
        ushort4 o;
        o.x = f2bf(v.x); o.y = f2bf(v.y); o.z = f2bf(v.z); o.w = f2bf(v.w);
        ((ushort4*)xb)[i] = o;
    }
}

__global__ void hist_deg(int* __restrict__ deg, const int* __restrict__ dsts, int nE) {
    int e = blockIdx.x * blockDim.x + threadIdx.x;
    if (e < nE) atomicAdd(&deg[dsts[e]], 1);
}

__global__ void scan_chunks(int* __restrict__ partial, int* __restrict__ sums,
                            const int* __restrict__ deg, int n) {
    int i = blockIdx.x * blockDim.x + threadIdx.x;
    int lane = threadIdx.x & 63;
    int v = (i < n) ? deg[i] : 0;
#pragma unroll
    for (int off = 1; off < 64; off <<= 1) {
        int t = __shfl_up(v, off);
        if (lane >= off) v += t;
    }
    if (i < n) partial[i] = v;
    if (lane == 63) sums[i >> 6] = v;
}

__global__ void scan_sums(int* __restrict__ offs, const int* __restrict__ sums, int nc) {
    int lane = threadIdx.x;  // 64 threads
    int carry = 0;
    for (int base = 0; base < nc; base += 64) {
        int idx = base + lane;
        int v = (idx < nc) ? sums[idx] : 0;
        int inc = v;
#pragma unroll
        for (int off = 1; off < 64; off <<= 1) {
            int t = __shfl_up(inc, off);
            if (lane >= off) inc += t;
        }
        if (idx < nc) offs[idx] = inc - v + carry;
        carry += __shfl(inc, 63);
    }
}

__global__ void finalize_rowptr(int* __restrict__ rowptr, int* __restrict__ cursor,
                                const int* __restrict__ partial, const int* __restrict__ offs,
                                const int* __restrict__ deg, int n) {
    int i = blockIdx.x * blockDim.x + threadIdx.x;
    if (i == 0) rowptr[0] = 0;
    if (i < n) {
        int incl = partial[i] + offs[i >> 6];
        rowptr[i + 1] = incl;
        cursor[i] = incl - deg[i];
    }
}

__global__ void fill_csr(int* __restrict__ csr, int* __restrict__ cursor,
                         const int* __restrict__ srcs, const int* __restrict__ dsts, int nE) {
    int e = blockIdx.x * blockDim.x + threadIdx.x;
    if (e >= nE) return;
    int d = dsts[e];
    int p = atomicAdd(&cursor[d], 1);
    csr[p] = srcs[e];
}

// ---------------------------------------------------------------------------
// gather (bf16): agg[n] = x[n] + sum_{j in csr row n} x[csr[j]]  (one wave/node)
__global__ __launch_bounds__(256) void gather_bf(u16* __restrict__ agg,
                                                 const u16* __restrict__ x,
                                                 const int* __restrict__ rowptr,
                                                 const int* __restrict__ csr, int nNodes) {
    int wid = (blockIdx.x * 256 + threadIdx.x) >> 6;
    int lane = threadIdx.x & 63;
    if (wid >= nNodes) return;
    const size_t coff = (size_t)lane * 2;
    ushort2 self = *(const ushort2*)(x + (size_t)wid * DIM + coff);
    float ax = bf2f(self.x), ay = bf2f(self.y);
    int beg = rowptr[wid], end = rowptr[wid + 1];
    int j = beg;
    for (; j + 4 <= end; j += 4) {
        int s0 = csr[j], s1 = csr[j + 1], s2 = csr[j + 2], s3 = csr[j + 3];
        ushort2 v0 = *(const ushort2*)(x + (size_t)s0 * DIM + coff);
        ushort2 v1 = *(const ushort2*)(x + (size_t)s1 * DIM + coff);
        ushort2 v2 = *(const ushort2*)(x + (size_t)s2 * DIM + coff);
        ushort2 v3 = *(const ushort2*)(x + (size_t)s3 * DIM + coff);
        ax += (bf2f(v0.x) + bf2f(v1.x)) + (bf2f(v2.x) + bf2f(v3.x));
        ay += (bf2f(v0.y) + bf2f(v1.y)) + (bf2f(v2.y) + bf2f(v3.y));
    }
    for (; j < end; ++j) {
        int s = csr[j];
        ushort2 v = *(const ushort2*)(x + (size_t)s * DIM + coff);
        ax += bf2f(v.x);
        ay += bf2f(v.y);
    }
    ushort2 o; o.x = f2bf(ax); o.y = f2bf(ay);
    *(ushort2*)(agg + (size_t)wid * DIM + coff) = o;
}

// ---------------------------------------------------------------------------
// Fused 2-layer MLP: out = relu(W2·relu(BN(W1·in + b1)) + b2), bf16 in/out.
// Block = 4 waves x 16 rows. H in wave-private LDS (no barriers).
__global__ __launch_bounds__(256) void mlp_fused(
    u16* __restrict__ out, const u16* __restrict__ in,
    const u16* __restrict__ W1f, const u16* __restrict__ W2f,
    const float* __restrict__ b1, const float* __restrict__ g1,
    const float* __restrict__ bt1, const float* __restrict__ b2, int nrows) {
    __shared__ u16 lds[4][16 * LSTRIDE];  // 17408 B
    const int wv = threadIdx.x >> 6;
    const int lane = threadIdx.x & 63;
    const int row0 = blockIdx.x * 64 + wv * 16;
    u16* H = lds[wv];

    const float inv = rsqrtf(1.f + 1e-5f);
    const int col0 = lane & 15;
    const int rb = (lane >> 4) << 2;
    const int fragoff = ((lane & 15) * LSTRIDE) + ((lane >> 4) << 3);

    // ---- GEMM1 + BN + ReLU -> H (LDS) ----
    {
        const int arow = min(row0 + (lane & 15), nrows - 1);
        const u16* ap = in + (size_t)arow * DIM + ((lane >> 4) << 3);
        f32x4 acc[8];
#pragma unroll
        for (int cb = 0; cb < 8; ++cb) acc[cb] = (f32x4){0.f, 0.f, 0.f, 0.f};
#pragma unroll
        for (int kc = 0; kc < 4; ++kc) {
            bf16x8 a = *(const bf16x8*)(ap + kc * 32);
#pragma unroll
            for (int cb = 0; cb < 8; ++cb) {
                bf16x8 bb = *(const bf16x8*)(W1f + ((((kc << 3) + cb) << 6 | lane) << 3));
                acc[cb] = __builtin_amdgcn_mfma_f32_16x16x32_bf16(a, bb, acc[cb], 0, 0, 0);
            }
        }
#pragma unroll
        for (int cb = 0; cb < 8; ++cb) {
            const int c = (cb << 4) + col0;
            const float bias = b1[c];
            const float sg = inv * g1[c];
            const float st = bt1[c];
#pragma unroll
            for (int q = 0; q < 4; ++q) {
                float v = (acc[cb][q] + bias) * sg + st;
                H[(rb + q) * LSTRIDE + c] = f2bf(fmaxf(v, 0.f));
            }
        }
    }

    // ---- GEMM2 + bias + ReLU -> H (reused as staging) ----
    {
        f32x4 acc[8];
#pragma unroll
        for (int cb = 0; cb < 8; ++cb) acc[cb] = (f32x4){0.f, 0.f, 0.f, 0.f};
#pragma unroll
        for (int kc = 0; kc < 4; ++kc) {
            bf16x8 a = *(const bf16x8*)&H[fragoff + kc * 32];
#pragma unroll
            for (int cb = 0; cb < 8; ++cb) {
                bf16x8 bb = *(const bf16x8*)(W2f + ((((kc << 3) + cb) << 6 | lane) << 3));
                acc[cb] = __builtin_amdgcn_mfma_f32_16x16x32_bf16(a, bb, acc[cb], 0, 0, 0);
            }
        }
#pragma unroll
        for (int cb = 0; cb < 8; ++cb) {
            const int c = (cb << 4) + col0;
            const float bias = b2[c];
#pragma unroll
            for (int q = 0; q < 4; ++q) {
                float v = acc[cb][q] + bias;
                H[(rb + q) * LSTRIDE + c] = f2bf(fmaxf(v, 0.f));
            }
        }
    }

    // ---- coalesced copy-out (2 rows / pass, 8B / lane) ----
#pragma unroll
    for (int it = 0; it < 8; ++it) {
        const int r = it * 2 + (lane >> 5);
        const int grow = row0 + r;
        const int m = lane & 31;
        uint2 v = *(const uint2*)&H[r * LSTRIDE + m * 4];
        if (grow < nrows) *(uint2*)(out + (size_t)grow * DIM + m * 4) = v;
    }
}

// ---------------------------------------------------------------------------
// pool stage 1: one wave per 16-node chunk; batch sorted -> few flushes.
// lane owns cols {2l, 2l+1}; flush = 2 f32 atomicAdds per lane per graph.
__global__ __launch_bounds__(256) void pool_partial(float* __restrict__ pooled,
                                                    const u16* __restrict__ x,
                                                    const int* __restrict__ batch) {
    const int chunk = (blockIdx.x * 256 + threadIdx.x) >> 6;
    const int lane = threadIdx.x & 63;
    const int beg = chunk * 16;
    if (beg >= N_NODES) return;
    const int end = min(beg + 16, N_NODES);
    const size_t coff = (size_t)lane * 2;

    float ax = 0.f, ay = 0.f;
    int curg = batch[beg];
    for (int n = beg; n < end; ++n) {
        int g = batch[n];
        if (g != curg) {
            atomicAdd(&pooled[(size_t)curg * DIM + coff], ax);
            atomicAdd(&pooled[(size_t)curg * DIM + coff + 1], ay);
            ax = 0.f; ay = 0.f; curg = g;
        }
        ushort2 v = *(const ushort2*)(x + (size_t)n * DIM + coff);
        ax += bf2f(v.x);
        ay += bf2f(v.y);
    }
    atomicAdd(&pooled[(size_t)curg * DIM + coff], ax);
    atomicAdd(&pooled[(size_t)curg * DIM + coff + 1], ay);
}

// pool stage 2: final MLP per graph
__global__ __launch_bounds__(128) void tail_mlp(float* __restrict__ out,
                                                const float* __restrict__ pooled,
                                                const float* __restrict__ mW1,
                                                const float* __restrict__ mb1,
                                                const float* __restrict__ mg,
                                                const float* __restrict__ mbt,
                                                const float* __restrict__ mW2,
                                                const float* __restrict__ mb2) {
    const int g = blockIdx.x;
    const int c = threadIdx.x;
    __shared__ float pl[DIM];
    __shared__ float hd[DIM];
    pl[c] = pooled[(size_t)g * DIM + c];
    __syncthreads();

    float s = 0.f;
#pragma unroll 4
    for (int k = 0; k < DIM; ++k) s += pl[k] * mW1[k * DIM + c];
    const float inv = rsqrtf(1.f + 1e-5f);
    s = (s + mb1[c]) * (inv * mg[c]) + mbt[c];
    hd[c] = fmaxf(s, 0.f);
    __syncthreads();

    if (c < NOUT) {
        float o = 0.f;
#pragma unroll 4
        for (int k = 0; k < DIM; ++k) o += hd[k] * mW2[k * NOUT + c];
        out[g * NOUT + c] = o + mb2[c];
    }
}

// ---------------------------------------------------------------------------
extern "C" void kernel_launch(void* const* d_in, const int* in_sizes, int n_in,
                              void* d_out, int out_size, void* d_ws, size_t ws_size,
                              hipStream_t stream) {
    const float* x      = (const float*)d_in[0];
    const int*   ei     = (const int*)d_in[1];
    const int*   batch  = (const int*)d_in[2];
    const float* convW1 = (const float*)d_in[3];
    const float* convb1 = (const float*)d_in[4];
    const float* convg  = (const float*)d_in[5];
    const float* convbt = (const float*)d_in[6];
    const float* convW2 = (const float*)d_in[7];
    const float* convb2 = (const float*)d_in[8];
    const float* mW1    = (const float*)d_in[9];
    const float* mb1    = (const float*)d_in[10];
    const float* mg     = (const float*)d_in[11];
    const float* mbt    = (const float*)d_in[12];
    const float* mW2    = (const float*)d_in[13];
    const float* mb2    = (const float*)d_in[14];
    float* out = (float*)d_out;

    const int* srcs = ei;
    const int* dsts = ei + N_EDGES;

    // workspace layout
    const size_t NF = (size_t)N_NODES * DIM;
    u16* xb0    = (u16*)d_ws;     // bf16 input features
    u16* aggbuf = xb0 + NF;
    u16* bufA   = aggbuf + NF;
    u16* bufB   = bufA + NF;
    u16* Wswz   = bufB + NF;      // 6*16384 bf16
    float* pooled = (float*)(Wswz + 6 * 16384);
    int* deg     = (int*)(pooled + N_GRAPHS * DIM);
    int* cursor  = deg + N_NODES;
    int* rowptr  = cursor + N_NODES;          // N_NODES+1
    int* partial = rowptr + (N_NODES + 1);
    int* sums    = partial + N_NODES;          // 1024 w/ slack
    int* offs    = sums + 1024;                // 1024
    int* csr     = offs + 1024;                // N_EDGES

    const int NCHUNK = (N_NODES + 63) / 64;

    // ---- init + CSR build ----
    init_all<<<(N_NODES * DIM / 4 + 255) / 256, 256, 0, stream>>>(deg, pooled, xb0, x, Wswz, convW1, convW2);
    hist_deg<<<(N_EDGES + 255) / 256, 256, 0, stream>>>(deg, dsts, N_EDGES);
    scan_chunks<<<(N_NODES + 255) / 256, 256, 0, stream>>>(partial, sums, deg, N_NODES);
    scan_sums<<<1, 64, 0, stream>>>(offs, sums, NCHUNK);
    finalize_rowptr<<<(N_NODES + 255) / 256, 256, 0, stream>>>(rowptr, cursor, partial, offs, deg, N_NODES);
    fill_csr<<<(N_EDGES + 255) / 256, 256, 0, stream>>>(csr, cursor, srcs, dsts, N_EDGES);

    // ---- 3 GIN layers: gather (high-TLP) + fused MLP (compute-dense) ----
    const int gatherBlocks = (N_NODES * 64 + 255) / 256;
    const int mlpBlocks    = (N_NODES + 63) / 64;
    const u16* cur = xb0;
    u16* nxt = bufA;
    for (int l = 0; l < NLAYERS; ++l) {
        gather_bf<<<gatherBlocks, 256, 0, stream>>>(aggbuf, cur, rowptr, csr, N_NODES);
        mlp_fused<<<mlpBlocks, 256, 0, stream>>>(
            nxt, aggbuf,
            Wswz + (size_t)l * 16384, Wswz + (size_t)(3 + l) * 16384,
            convb1 + l * DIM, convg + l * DIM, convbt + l * DIM, convb2 + l * DIM, N_NODES);
        cur = nxt;
        nxt = (nxt == bufA) ? bufB : bufA;
    }

    // ---- pool (2-stage) + final MLP ----
    const int poolBlocks = ((N_NODES + 15) / 16 * 64 + 255) / 256;
    pool_partial<<<poolBlocks, 256, 0, stream>>>(pooled, cur, batch);
    tail_mlp<<<N_GRAPHS, 128, 0, stream>>>(out, pooled, mW1, mb1, mg, mbt, mW2, mb2);
}

// Round 8
// 197.410 us; speedup vs baseline: 1.5679x; 1.2530x over previous
//
#include <hip/hip_runtime.h>

#define N_NODES 50000
#define N_EDGES 600000
#define N_GRAPHS 128
#define DIM 128
#define NLAYERS 3
#define NOUT 10
#define ELLW 48      // max degree slot count (P(overflow) ~ 1e-21, writes clamped)
#define LSTRIDE 136  // LDS row stride in bf16 elems (272B: 16B-aligned rows)

typedef unsigned short u16;
typedef __attribute__((ext_vector_type(8))) short bf16x8;
typedef __attribute__((ext_vector_type(4))) float f32x4;

__device__ __forceinline__ float bf2f(u16 v) {
    unsigned u = ((unsigned)v) << 16;
    return __builtin_bit_cast(float, u);
}
__device__ __forceinline__ u16 f2bf(float f) {  // round-to-nearest-even
    unsigned u = __builtin_bit_cast(unsigned, f);
    u = u + 0x7fffu + ((u >> 16) & 1u);
    return (u16)(u >> 16);
}

// ---------------------------------------------------------------------------
// init: deg=0, pooled=0, x->bf16, W pre-swizzle into MFMA B-fragment order
__global__ void init_all(int* __restrict__ deg, float* __restrict__ pooled,
                         u16* __restrict__ xb, const float* __restrict__ x,
                         u16* __restrict__ Wswz,
                         const float* __restrict__ convW1, const float* __restrict__ convW2) {
    int i = blockIdx.x * blockDim.x + threadIdx.x;
    if (i < N_NODES) deg[i] = 0;
    if (i < N_GRAPHS * DIM) pooled[i] = 0.f;
    if (i < 6 * 16384) {
        int j = i & 7, lane = (i >> 3) & 63, cb = (i >> 9) & 7, kc = (i >> 12) & 3, w = i >> 14;
        int k = kc * 32 + ((lane >> 4) << 3) + j;
        int c = (cb << 4) + (lane & 15);
        const float* W = (w < 3) ? (convW1 + (size_t)w * 16384) : (convW2 + (size_t)(w - 3) * 16384);
        Wswz[i] = f2bf(W[k * DIM + c]);
    }
    if (i < N_NODES * DIM / 4) {
        float4 v = ((const float4*)x)[i];
        ushort4 o;
        o.x = f2bf(v.x); o.y = f2bf(v.y); o.z = f2bf(v.z); o.w = f2bf(v.w);
        ((ushort4*)xb)[i] = o;
    }
}

// ---------------------------------------------------------------------------
// ELL build in ONE kernel: slot = deg[d]++; ell[d][slot] = src  (no scan!)
__global__ void fill_ell(int* __restrict__ deg, int* __restrict__ ell,
                         const int* __restrict__ srcs, const int* __restrict__ dsts, int nE) {
    int e = blockIdx.x * blockDim.x + threadIdx.x;
    if (e >= nE) return;
    int d = dsts[e];
    int slot = atomicAdd(&deg[d], 1);
    if (slot < ELLW) ell[(size_t)d * ELLW + slot] = srcs[e];
}

// ---------------------------------------------------------------------------
// Fused GIN layer: out = relu(MLP2(relu(BN(MLP1(x + ELL-gather(x))))))
// 512 threads = 8 waves; tile 32 rows. Gather: each wave does 4 rows (short
// serial chain) at 4 blocks/CU = 32 waves/CU TLP. MFMA: 2 row-tiles x 4
// col-groups; wave (rt,cg) computes rows rt*16..+15, cols cg*32..+31.
__global__ __launch_bounds__(512) void layer_fused(
    u16* __restrict__ out, const u16* __restrict__ x,
    const int* __restrict__ deg, const int* __restrict__ ell,
    const u16* __restrict__ W1f, const u16* __restrict__ W2f,
    const float* __restrict__ b1, const float* __restrict__ g1,
    const float* __restrict__ bt1, const float* __restrict__ b2) {
    __shared__ u16 A[32 * LSTRIDE];  // 8704 B
    __shared__ u16 H[32 * LSTRIDE];  // 8704 B
    const int tid = threadIdx.x;
    const int wv = tid >> 6;
    const int lane = tid & 63;
    const int row0 = blockIdx.x * 32;

    // ---- phase 1: gather (wave wv -> rows wv*4..wv*4+3) ----
    const size_t coff = (size_t)lane * 2;
#pragma unroll
    for (int i = 0; i < 4; ++i) {
        const int r = (wv << 2) + i;
        const int grow = row0 + r;
        float ax = 0.f, ay = 0.f;
        if (grow < N_NODES) {
            ushort2 self = *(const ushort2*)(x + (size_t)grow * DIM + coff);
            ax = bf2f(self.x); ay = bf2f(self.y);
            const int len = min(deg[grow], ELLW);
            const int* ep = ell + (size_t)grow * ELLW;
            int j = 0;
            for (; j + 4 <= len; j += 4) {
                int s0 = ep[j], s1 = ep[j + 1], s2 = ep[j + 2], s3 = ep[j + 3];
                ushort2 v0 = *(const ushort2*)(x + (size_t)s0 * DIM + coff);
                ushort2 v1 = *(const ushort2*)(x + (size_t)s1 * DIM + coff);
                ushort2 v2 = *(const ushort2*)(x + (size_t)s2 * DIM + coff);
                ushort2 v3 = *(const ushort2*)(x + (size_t)s3 * DIM + coff);
                ax += (bf2f(v0.x) + bf2f(v1.x)) + (bf2f(v2.x) + bf2f(v3.x));
                ay += (bf2f(v0.y) + bf2f(v1.y)) + (bf2f(v2.y) + bf2f(v3.y));
            }
            for (; j < len; ++j) {
                int s = ep[j];
                ushort2 v = *(const ushort2*)(x + (size_t)s * DIM + coff);
                ax += bf2f(v.x);
                ay += bf2f(v.y);
            }
        }
        ushort2 o; o.x = f2bf(ax); o.y = f2bf(ay);
        *(ushort2*)&A[r * LSTRIDE + lane * 2] = o;
    }
    __syncthreads();

    // ---- MFMA phase setup ----
    const int rt = wv >> 2;   // row-tile 0..1
    const int cg = wv & 3;    // col-group 0..3 (cb = 2cg, 2cg+1)
    const float inv = rsqrtf(1.f + 1e-5f);
    const int col0 = lane & 15;
    const int rbl = (rt << 4) + ((lane >> 4) << 2);  // local C/D row base
    const int fragoff = ((rt << 4) + (lane & 15)) * LSTRIDE + ((lane >> 4) << 3);

    // ---- phase 2: GEMM1 + BN + ReLU -> H ----
    {
        f32x4 acc[2];
        acc[0] = (f32x4){0.f, 0.f, 0.f, 0.f};
        acc[1] = (f32x4){0.f, 0.f, 0.f, 0.f};
#pragma unroll
        for (int kc = 0; kc < 4; ++kc) {
            bf16x8 a = *(const bf16x8*)&A[fragoff + kc * 32];
#pragma unroll
            for (int m = 0; m < 2; ++m) {
                const int cb = (cg << 1) + m;
                bf16x8 bb = *(const bf16x8*)(W1f + ((((kc << 3) + cb) << 6 | lane) << 3));
                acc[m] = __builtin_amdgcn_mfma_f32_16x16x32_bf16(a, bb, acc[m], 0, 0, 0);
            }
        }
#pragma unroll
        for (int m = 0; m < 2; ++m) {
            const int c = (((cg << 1) + m) << 4) + col0;
            const float bias = b1[c];
            const float sg = inv * g1[c];
            const float st = bt1[c];
#pragma unroll
            for (int q = 0; q < 4; ++q) {
                float v = (acc[m][q] + bias) * sg + st;
                H[(rbl + q) * LSTRIDE + c] = f2bf(fmaxf(v, 0.f));
            }
        }
    }
    __syncthreads();

    // ---- phase 3: GEMM2 + bias + ReLU -> A (A is dead now; reuse as staging) ----
    {
        f32x4 acc[2];
        acc[0] = (f32x4){0.f, 0.f, 0.f, 0.f};
        acc[1] = (f32x4){0.f, 0.f, 0.f, 0.f};
#pragma unroll
        for (int kc = 0; kc < 4; ++kc) {
            bf16x8 a = *(const bf16x8*)&H[fragoff + kc * 32];
#pragma unroll
            for (int m = 0; m < 2; ++m) {
                const int cb = (cg << 1) + m;
                bf16x8 bb = *(const bf16x8*)(W2f + ((((kc << 3) + cb) << 6 | lane) << 3));
                acc[m] = __builtin_amdgcn_mfma_f32_16x16x32_bf16(a, bb, acc[m], 0, 0, 0);
            }
        }
#pragma unroll
        for (int m = 0; m < 2; ++m) {
            const int c = (((cg << 1) + m) << 4) + col0;
            const float bias = b2[c];
#pragma unroll
            for (int q = 0; q < 4; ++q) {
                float v = acc[m][q] + bias;
                A[(rbl + q) * LSTRIDE + c] = f2bf(fmaxf(v, 0.f));
            }
        }
    }
    __syncthreads();

    // ---- phase 4: coalesced copy-out (512 thr x 16B = full 32x128 tile) ----
    {
        const int r = tid >> 4;        // 0..31
        const int seg = tid & 15;      // 16B column segment
        const int grow = row0 + r;
        uint4 v = *(const uint4*)&A[r * LSTRIDE + seg * 8];
        if (grow < N_NODES) *(uint4*)(out + (size_t)grow * DIM + seg * 8) = v;
    }
}

// ---------------------------------------------------------------------------
// pool stage 1: one wave per 16-node chunk; batch sorted -> few flushes.
__global__ __launch_bounds__(256) void pool_partial(float* __restrict__ pooled,
                                                    const u16* __restrict__ x,
                                                    const int* __restrict__ batch) {
    const int chunk = (blockIdx.x * 256 + threadIdx.x) >> 6;
    const int lane = threadIdx.x & 63;
    const int beg = chunk * 16;
    if (beg >= N_NODES) return;
    const int end = min(beg + 16, N_NODES);
    const size_t coff = (size_t)lane * 2;

    float ax = 0.f, ay = 0.f;
    int curg = batch[beg];
    for (int n = beg; n < end; ++n) {
        int g = batch[n];
        if (g != curg) {
            atomicAdd(&pooled[(size_t)curg * DIM + coff], ax);
            atomicAdd(&pooled[(size_t)curg * DIM + coff + 1], ay);
            ax = 0.f; ay = 0.f; curg = g;
        }
        ushort2 v = *(const ushort2*)(x + (size_t)n * DIM + coff);
        ax += bf2f(v.x);
        ay += bf2f(v.y);
    }
    atomicAdd(&pooled[(size_t)curg * DIM + coff], ax);
    atomicAdd(&pooled[(size_t)curg * DIM + coff + 1], ay);
}

// pool stage 2: final MLP per graph
__global__ __launch_bounds__(128) void tail_mlp(float* __restrict__ out,
                                                const float* __restrict__ pooled,
                                                const float* __restrict__ mW1,
                                                const float* __restrict__ mb1,
                                                const float* __restrict__ mg,
                                                const float* __restrict__ mbt,
                                                const float* __restrict__ mW2,
                                                const float* __restrict__ mb2) {
    const int g = blockIdx.x;
    const int c = threadIdx.x;
    __shared__ float pl[DIM];
    __shared__ float hd[DIM];
    pl[c] = pooled[(size_t)g * DIM + c];
    __syncthreads();

    float s = 0.f;
#pragma unroll 4
    for (int k = 0; k < DIM; ++k) s += pl[k] * mW1[k * DIM + c];
    const float inv = rsqrtf(1.f + 1e-5f);
    s = (s + mb1[c]) * (inv * mg[c]) + mbt[c];
    hd[c] = fmaxf(s, 0.f);
    __syncthreads();

    if (c < NOUT) {
        float o = 0.f;
#pragma unroll 4
        for (int k = 0; k < DIM; ++k) o += hd[k] * mW2[k * NOUT + c];
        out[g * NOUT + c] = o + mb2[c];
    }
}

// ---------------------------------------------------------------------------
extern "C" void kernel_launch(void* const* d_in, const int* in_sizes, int n_in,
                              void* d_out, int out_size, void* d_ws, size_t ws_size,
                              hipStream_t stream) {
    const float* x      = (const float*)d_in[0];
    const int*   ei     = (const int*)d_in[1];
    const int*   batch  = (const int*)d_in[2];
    const float* convW1 = (const float*)d_in[3];
    const float* convb1 = (const float*)d_in[4];
    const float* convg  = (const float*)d_in[5];
    const float* convbt = (const float*)d_in[6];
    const float* convW2 = (const float*)d_in[7];
    const float* convb2 = (const float*)d_in[8];
    const float* mW1    = (const float*)d_in[9];
    const float* mb1    = (const float*)d_in[10];
    const float* mg     = (const float*)d_in[11];
    const float* mbt    = (const float*)d_in[12];
    const float* mW2    = (const float*)d_in[13];
    const float* mb2    = (const float*)d_in[14];
    float* out = (float*)d_out;

    const int* srcs = ei;
    const int* dsts = ei + N_EDGES;

    // workspace layout
    const size_t NF = (size_t)N_NODES * DIM;
    u16* xb0  = (u16*)d_ws;       // bf16 input features
    u16* bufA = xb0 + NF;
    u16* bufB = bufA + NF;
    u16* Wswz = bufB + NF;        // 6*16384 bf16
    float* pooled = (float*)(Wswz + 6 * 16384);
    int* deg = (int*)(pooled + N_GRAPHS * DIM);
    int* ell = deg + N_NODES;     // N_NODES * ELLW

    // ---- init + ELL build (2 kernels; no scan chain) ----
    init_all<<<(N_NODES * DIM / 4 + 255) / 256, 256, 0, stream>>>(deg, pooled, xb0, x, Wswz, convW1, convW2);
    fill_ell<<<(N_EDGES + 255) / 256, 256, 0, stream>>>(deg, ell, srcs, dsts, N_EDGES);

    // ---- 3 fused GIN layers ----
    const int layerBlocks = (N_NODES + 31) / 32;
    const u16* cur = xb0;
    u16* nxt = bufA;
    for (int l = 0; l < NLAYERS; ++l) {
        layer_fused<<<layerBlocks, 512, 0, stream>>>(
            nxt, cur, deg, ell,
            Wswz + (size_t)l * 16384, Wswz + (size_t)(3 + l) * 16384,
            convb1 + l * DIM, convg + l * DIM, convbt + l * DIM, convb2 + l * DIM);
        cur = nxt;
        nxt = (nxt == bufA) ? bufB : bufA;
    }

    // ---- pool (2-stage) + final MLP ----
    const int poolBlocks = ((N_NODES + 15) / 16 * 64 + 255) / 256;
    pool_partial<<<poolBlocks, 256, 0, stream>>>(pooled, cur, batch);
    tail_mlp<<<N_GRAPHS, 128, 0, stream>>>(out, pooled, mW1, mb1, mg, mbt, mW2, mb2);
}